// Round 10
// baseline (424.243 us; speedup 1.0000x reference)
//
#include <hip/hip_runtime.h>

#define B_     8
#define C_     256
#define H_     64
#define W_     64
#define HEADS_ 4
#define DH_    64
#define TQ_    4096   // 64*64 query pixels
#define TKV_   1024   // 32*32 kv pixels
#define EPS_   1e-5f
#define SCALE_ 0.0625f  // 256^-0.5

typedef __attribute__((ext_vector_type(8))) short short8;
typedef __attribute__((ext_vector_type(4))) float f32x4;

#define MFMA(a, b, c) __builtin_amdgcn_mfma_f32_16x16x32_bf16((a), (b), (c), 0, 0, 0)

static __device__ __forceinline__ unsigned short f2bf(float x) {
    unsigned u = __float_as_uint(x);
    u += 0x7fff + ((u >> 16) & 1);          // round-to-nearest-even
    return (unsigned short)(u >> 16);
}
static __device__ __forceinline__ float bf2f(unsigned short h) {
    return __uint_as_float(((unsigned)h) << 16);
}
// async global->LDS, 16B per lane; LDS dest is wave-uniform base + lane*16
#define GLOAD16(gp, lp) __builtin_amdgcn_global_load_lds(                      \
    (const __attribute__((address_space(1))) void*)(gp),                       \
    (__attribute__((address_space(3))) void*)(lp), 16, 0, 0)

// ---------------------------------------------------------------------------
// one-shot fp32 -> bf16 hi/lo split of the 4 weight matrices (row-major kept)
// grid (64, 4): blockIdx.y selects the matrix
// ---------------------------------------------------------------------------
__global__ __launch_bounds__(256)
void w2bf4_kernel(const float* __restrict__ w0, const float* __restrict__ w1,
                  const float* __restrict__ w2, const float* __restrict__ w3,
                  unsigned short* __restrict__ h0, unsigned short* __restrict__ l0,
                  unsigned short* __restrict__ h1, unsigned short* __restrict__ l1,
                  unsigned short* __restrict__ h2, unsigned short* __restrict__ l2,
                  unsigned short* __restrict__ h3, unsigned short* __restrict__ l3) {
    int m = blockIdx.y;
    const float* wm = (m == 0) ? w0 : (m == 1) ? w1 : (m == 2) ? w2 : w3;
    unsigned short* whi = (m == 0) ? h0 : (m == 1) ? h1 : (m == 2) ? h2 : h3;
    unsigned short* wlo = (m == 0) ? l0 : (m == 1) ? l1 : (m == 2) ? l2 : l3;
    int idx = (blockIdx.x * 256 + threadIdx.x) * 4;
    const float4 v4 = *(const float4*)&wm[idx];
    float vv[4] = {v4.x, v4.y, v4.z, v4.w};
    unsigned short hh[4], ll[4];
    #pragma unroll
    for (int j = 0; j < 4; ++j) { hh[j] = f2bf(vv[j]); ll[j] = f2bf(vv[j] - bf2f(hh[j])); }
    *(ushort4*)&whi[idx] = make_ushort4(hh[0], hh[1], hh[2], hh[3]);
    *(ushort4*)&wlo[idx] = make_ushort4(ll[0], ll[1], ll[2], ll[3]);
}

// ---------------------------------------------------------------------------
// all three depthwise 3x3 + BN paths in ONE launch; block range selects path.
//   [0,32768)      : q path, stride 1, 64x64 -> yq
//   [32768,40960)  : k path, stride 2, 32x32 -> yk
//   [40960,49152)  : v path, stride 2, 32x32 -> yv
// out layout [b][c][p]
// ---------------------------------------------------------------------------
__global__ __launch_bounds__(256)
void dwbn3_kernel(const float* __restrict__ x,
                  const float* __restrict__ dwq, const float* __restrict__ gq,
                  const float* __restrict__ bq,  const float* __restrict__ mq,
                  const float* __restrict__ vq,  float* __restrict__ yq,
                  const float* __restrict__ dwk, const float* __restrict__ gk,
                  const float* __restrict__ bk,  const float* __restrict__ mk,
                  const float* __restrict__ vk,  float* __restrict__ yk,
                  const float* __restrict__ dwv, const float* __restrict__ gv,
                  const float* __restrict__ bv,  const float* __restrict__ mv,
                  const float* __restrict__ vv,  float* __restrict__ yv) {
    int bid = blockIdx.x;
    const float *dw, *g, *bet, *mu, *var;
    float* y;
    int stride, Ho, Wo, base;
    if (bid < 32768) {
        dw = dwq; g = gq; bet = bq; mu = mq; var = vq; y = yq;
        stride = 1; Ho = 64; Wo = 64; base = 0;
    } else if (bid < 40960) {
        dw = dwk; g = gk; bet = bk; mu = mk; var = vk; y = yk;
        stride = 2; Ho = 32; Wo = 32; base = 32768;
    } else {
        dw = dwv; g = gv; bet = bv; mu = mv; var = vv; y = yv;
        stride = 2; Ho = 32; Wo = 32; base = 40960;
    }
    int idx = (bid - base) * 256 + threadIdx.x;
    int ow = idx % Wo;
    int t  = idx / Wo;
    int oh = t % Ho; t /= Ho;
    int c  = t % C_;
    int b  = t / C_;
    const float* xp = x + ((size_t)(b * C_ + c)) * H_ * W_;
    const float* wp = dw + c * 9;
    int ih0 = oh * stride - 1, iw0 = ow * stride - 1;
    float acc = 0.f;
    #pragma unroll
    for (int kh = 0; kh < 3; ++kh) {
        int ih = ih0 + kh;
        if (ih < 0 || ih >= H_) continue;
        #pragma unroll
        for (int kw = 0; kw < 3; ++kw) {
            int iw = iw0 + kw;
            if (iw < 0 || iw >= W_) continue;
            acc = fmaf(xp[ih * W_ + iw], wp[kh * 3 + kw], acc);
        }
    }
    float inv = g[c] * __frsqrt_rn(var[c] + EPS_);
    y[idx] = (acc - mu[c]) * inv + bet[c];
}

// ---------------------------------------------------------------------------
// pointwise GEMM on MFMA, split-bf16 (hi/lo, 3 products), per batch:
//   D[o][p] = sum_c W[o][c] * Y[c][p]
// block 256 thr (4 waves), tile 64o x 64p, K-chunks of 64.
// A (W) is pre-split bf16 [o][c]: staged via global_load_lds, source-XOR swz.
// IN_BF16: 0 = Y fp32 [c][p] (transpose+convert via LDS scratch)
//          1 = Y bf16 hi/lo [p][c] (global_load_lds, source-XOR swizzle)
// OUT_MODE: 0 = bf16 hi/lo pixel-major [b][p][o]
//           1 = bf16 hi/lo channel-major [b][o][p]
//           2 = fp32 channel-major + bias (final output)
// LDS tiles: chunk slot s of row r holds global chunk s^(r&7); reads XOR back.
// MFMA frags: A row = lane&15, B col = lane&15; A/B use the same
// (group,elem)->k bijection so the K-sum is order-invariant;
// D: col = lane&15, row = (lane>>4)*4 + reg   [HW-verified m89/m91]
// ---------------------------------------------------------------------------
template<int IN_BF16, int OUT_MODE>
__global__ __launch_bounds__(256, 2)
void pw_mfma(const unsigned short* __restrict__ whi, const unsigned short* __restrict__ wlo,
             const float* __restrict__ yf32,
             const unsigned short* __restrict__ yhi, const unsigned short* __restrict__ ylo,
             unsigned short* __restrict__ ohi, unsigned short* __restrict__ olo,
             float* __restrict__ of32, const float* __restrict__ bias, int Np) {
    __shared__ unsigned short Ah[64 * 64], Al[64 * 64];
    __shared__ unsigned short Bh[64 * 64], Bl[64 * 64];
    __shared__ float scr[64 * 64];   // fp32 staging / epilogue transpose (swizzled)

    const int tid = threadIdx.x;
    const int l = tid & 63, w = tid >> 6;
    const int g = l >> 4, ln = l & 15;
    const int pbase = blockIdx.x * 64;
    const int obase = blockIdx.y * 64;
    const int b = blockIdx.z;

    f32x4 acc[4];
    #pragma unroll
    for (int f = 0; f < 4; ++f) acc[f] = (f32x4){0.f, 0.f, 0.f, 0.f};

    for (int c0 = 0; c0 < C_; c0 += 64) {
        // ---- stage A: pre-split W bf16 [o][c] via global_load_lds ----
        #pragma unroll
        for (int ii = 0; ii < 4; ++ii) {
            int ch = w * 4 + ii;  // 0..15: 0-7 hi, 8-15 lo
            const unsigned short* src = (ch < 8) ? whi : wlo;
            unsigned short* dst = (ch < 8) ? Ah : Al;
            int i = ch & 7;
            size_t ge = (size_t)(obase + i * 8 + (l >> 3)) * C_ + c0 +
                        (((l & 7) ^ ((l >> 3) & 7)) * 8);
            GLOAD16(src + ge, dst + i * 512);
        }
        if constexpr (IN_BF16) {
            // ---- stage B: bf16 [p][c] via global_load_lds, source-chunk XOR ----
            #pragma unroll
            for (int ii = 0; ii < 4; ++ii) {
                int ch = w * 4 + ii;
                const unsigned short* src = (ch < 8) ? yhi : ylo;
                unsigned short* dst = (ch < 8) ? Bh : Bl;
                int i = ch & 7;
                size_t ge = ((size_t)b * Np + pbase + i * 8 + (l >> 3)) * C_ + c0 +
                            (((l & 7) ^ ((l >> 3) & 7)) * 8);
                GLOAD16(src + ge, dst + i * 512);
            }
        } else {
            // ---- stage scratch: Y fp32 [c][p] tile, coalesced ----
            #pragma unroll
            for (int pass = 0; pass < 4; ++pass) {
                int idx = tid + pass * 256;
                int cr = idx >> 4, p4 = (idx & 15) * 4;
                *(float4*)&scr[cr * 64 + p4] =
                    *(const float4*)&yf32[(size_t)b * C_ * Np + (size_t)(c0 + cr) * Np + pbase + p4];
            }
        }
        __syncthreads();
        if constexpr (!IN_BF16) {
            // ---- transpose + convert: scratch [c][p] -> B hi/lo [p][c] swizzled ----
            int p = tid & 63, cq = tid >> 6;
            #pragma unroll
            for (int jj = 0; jj < 4; ++jj) {
                unsigned short hh[4], ll[4];
                #pragma unroll
                for (int j = 0; j < 4; ++j) {
                    float v = scr[(cq * 16 + jj * 4 + j) * 64 + p];
                    hh[j] = f2bf(v); ll[j] = f2bf(v - bf2f(hh[j]));
                }
                int cl = cq * 16 + jj * 4;
                int e = p * 64 + (((cl >> 3) ^ (p & 7)) * 8) + (cl & 7);
                *(ushort4*)&Bh[e] = make_ushort4(hh[0], hh[1], hh[2], hh[3]);
                *(ushort4*)&Bl[e] = make_ushort4(ll[0], ll[1], ll[2], ll[3]);
            }
            __syncthreads();
        }
        // ---- compute: 24 MFMA per K-chunk per wave ----
        #pragma unroll
        for (int kh = 0; kh < 2; ++kh) {
            int gc = kh * 4 + g;
            int ea = (16 * w + ln) * 64 + ((gc ^ (ln & 7)) * 8);
            short8 ah = *(const short8*)&Ah[ea];
            short8 al = *(const short8*)&Al[ea];
            #pragma unroll
            for (int f = 0; f < 4; ++f) {
                int p = f * 16 + ln;
                int eb = p * 64 + ((gc ^ (p & 7)) * 8);
                short8 bh = *(const short8*)&Bh[eb];
                short8 bl = *(const short8*)&Bl[eb];
                acc[f] = MFMA(ah, bh, acc[f]);
                acc[f] = MFMA(ah, bl, acc[f]);
                acc[f] = MFMA(al, bh, acc[f]);
            }
        }
        __syncthreads();
    }

    // ---- epilogues ----
    if constexpr (OUT_MODE == 0) {
        // transpose D [o][p] -> [p][o] via swizzled LDS, store bf16 hi/lo [b][p][o]
        #pragma unroll
        for (int f = 0; f < 4; ++f) {
            int p = f * 16 + ln;
            #pragma unroll
            for (int r = 0; r < 4; ++r) {
                int o = 16 * w + 4 * g + r;
                scr[p * 64 + (o ^ (4 * (p & 7)))] = acc[f][r];
            }
        }
        __syncthreads();
        int p = tid & 63, oq = tid >> 6;
        #pragma unroll
        for (int jj = 0; jj < 4; ++jj) {
            unsigned short hh[4], ll[4];
            #pragma unroll
            for (int j = 0; j < 4; ++j) {
                float v = scr[p * 64 + ((oq * 16 + jj * 4 + j) ^ (4 * (p & 7)))];
                hh[j] = f2bf(v); ll[j] = f2bf(v - bf2f(hh[j]));
            }
            size_t ge = ((size_t)b * Np + pbase + p) * C_ + obase + oq * 16 + jj * 4;
            *(ushort4*)&ohi[ge] = make_ushort4(hh[0], hh[1], hh[2], hh[3]);
            *(ushort4*)&olo[ge] = make_ushort4(ll[0], ll[1], ll[2], ll[3]);
        }
    } else if constexpr (OUT_MODE == 1) {
        #pragma unroll
        for (int f = 0; f < 4; ++f) {
            int p = pbase + f * 16 + ln;
            #pragma unroll
            for (int r = 0; r < 4; ++r) {
                int o = obase + 16 * w + 4 * g + r;
                size_t ge = ((size_t)b * C_ + o) * Np + p;
                float v = acc[f][r];
                unsigned short hh = f2bf(v);
                ohi[ge] = hh; olo[ge] = f2bf(v - bf2f(hh));
            }
        }
    } else {
        float bv[4];
        #pragma unroll
        for (int r = 0; r < 4; ++r) bv[r] = bias[obase + 16 * w + 4 * g + r];
        #pragma unroll
        for (int f = 0; f < 4; ++f) {
            int p = pbase + f * 16 + ln;
            #pragma unroll
            for (int r = 0; r < 4; ++r) {
                int o = obase + 16 * w + 4 * g + r;
                of32[((size_t)b * C_ + o) * Np + p] = acc[f][r] + bv[r];
            }
        }
    }
}

// ---------------------------------------------------------------------------
// flash attention on MFMA, split-bf16. q/k: [b][pix][c] hi/lo; v: [b][c][pix];
// out: [b][pix][c] hi/lo. Block = (b, head, 64-q tile), 4 waves x 16 q-rows.
// Q held in regs; K/V staged via global_load_lds (source-XOR swizzled);
// P in XOR-swizzled LDS [64][64] (slot = chunk ^ (qrow&7)), wave-private rows.
// LDS 48KB.
// ---------------------------------------------------------------------------
__global__ __launch_bounds__(256, 2)
void attn_mfma(const unsigned short* __restrict__ qhi, const unsigned short* __restrict__ qlo,
               const unsigned short* __restrict__ khi, const unsigned short* __restrict__ klo,
               const unsigned short* __restrict__ vhi, const unsigned short* __restrict__ vlo,
               unsigned short* __restrict__ ohi, unsigned short* __restrict__ olo) {
    __shared__ unsigned short Kh[64 * 64], Kl[64 * 64];
    __shared__ unsigned short Vh[64 * 64], Vl[64 * 64];
    __shared__ unsigned short Ph[64 * 64], Pl[64 * 64];

    const int tid = threadIdx.x, l = tid & 63, w = tid >> 6;
    const int g = l >> 4, ln = l & 15;
    const int qbase = blockIdx.x * 64;
    const int h = blockIdx.y, b = blockIdx.z;

    // Q fragments in regs: [16q x 64d] per wave, hi/lo x 2 k-halves
    short8 qh[2], ql[2];
    {
        size_t base = ((size_t)b * TQ_ + qbase + 16 * w + ln) * C_ + h * DH_ + g * 8;
        qh[0] = *(const short8*)&qhi[base];
        qh[1] = *(const short8*)&qhi[base + 32];
        ql[0] = *(const short8*)&qlo[base];
        ql[1] = *(const short8*)&qlo[base + 32];
    }
    f32x4 oacc[4];
    float m_run[4], l_run[4];
    #pragma unroll
    for (int f = 0; f < 4; ++f) oacc[f] = (f32x4){0.f, 0.f, 0.f, 0.f};
    #pragma unroll
    for (int r = 0; r < 4; ++r) { m_run[r] = -1e30f; l_run[r] = 0.f; }

    for (int kt = 0; kt < TKV_; kt += 64) {
        // stage K/V hi/lo: wave w owns one buffer (8 x 1KB chunks)
        {
            const unsigned short* src = (w == 0) ? khi : (w == 1) ? klo : (w == 2) ? vhi : vlo;
            unsigned short* dst = (w == 0) ? Kh : (w == 1) ? Kl : (w == 2) ? Vh : Vl;
            int swz = ((l & 7) ^ ((l >> 3) & 7)) * 8;
            if (w < 2) {   // K: rows = kv pixels, stride C_
                size_t base = ((size_t)b * TKV_ + kt) * C_ + h * DH_;
                #pragma unroll
                for (int i = 0; i < 8; ++i)
                    GLOAD16(src + base + (size_t)(i * 8 + (l >> 3)) * C_ + swz, dst + i * 512);
            } else {       // V: rows = d channels, stride TKV_
                size_t base = ((size_t)b * C_ + h * DH_) * TKV_ + kt;
                #pragma unroll
                for (int i = 0; i < 8; ++i)
                    GLOAD16(src + base + (size_t)(i * 8 + (l >> 3)) * TKV_ + swz, dst + i * 512);
            }
        }
        __syncthreads();

        // S = Q K^T: per wave 16q x 64kv
        f32x4 sacc[4];
        #pragma unroll
        for (int f = 0; f < 4; ++f) sacc[f] = (f32x4){0.f, 0.f, 0.f, 0.f};
        #pragma unroll
        for (int kh = 0; kh < 2; ++kh) {
            #pragma unroll
            for (int f = 0; f < 4; ++f) {
                int row = f * 16 + ln;   // kv
                int e = row * 64 + (((g + 4 * kh) ^ (ln & 7)) * 8);
                short8 bh = *(const short8*)&Kh[e];
                short8 bl = *(const short8*)&Kl[e];
                sacc[f] = MFMA(qh[kh], bh, sacc[f]);
                sacc[f] = MFMA(qh[kh], bl, sacc[f]);
                sacc[f] = MFMA(ql[kh], bh, sacc[f]);
            }
        }
        // online softmax; rows r -> q = 16w + 4g + r; kv = kt + f*16 + ln
        #pragma unroll
        for (int r = 0; r < 4; ++r) {
            float mm = fmaxf(fmaxf(sacc[0][r], sacc[1][r]), fmaxf(sacc[2][r], sacc[3][r]));
            #pragma unroll
            for (int off = 1; off < 16; off <<= 1) mm = fmaxf(mm, __shfl_xor(mm, off, 16));
            float mnew = fmaxf(m_run[r], mm * SCALE_);
            float corr = __expf(m_run[r] - mnew);
            float pv[4], rs = 0.f;
            #pragma unroll
            for (int f = 0; f < 4; ++f) { pv[f] = __expf(sacc[f][r] * SCALE_ - mnew); rs += pv[f]; }
            #pragma unroll
            for (int off = 1; off < 16; off <<= 1) rs += __shfl_xor(rs, off, 16);
            l_run[r] = l_run[r] * corr + rs;
            m_run[r] = mnew;
            #pragma unroll
            for (int f = 0; f < 4; ++f) oacc[f][r] *= corr;
            int q = 16 * w + 4 * g + r;
            #pragma unroll
            for (int f = 0; f < 4; ++f) {
                unsigned short hh = f2bf(pv[f]);
                int e = q * 64 + (((f * 2 + (ln >> 3)) ^ (q & 7)) * 8) + (ln & 7);
                Ph[e] = hh;
                Pl[e] = f2bf(pv[f] - bf2f(hh));
            }
        }
        __syncthreads();   // P visible, K reads done

        // O += P V: per wave 16q x 64d
        #pragma unroll
        for (int kvh = 0; kvh < 2; ++kvh) {
            int qr = 16 * w + ln;
            int pe = qr * 64 + (((kvh * 4 + g) ^ (qr & 7)) * 8);
            short8 ph = *(const short8*)&Ph[pe];
            short8 pl = *(const short8*)&Pl[pe];
            #pragma unroll
            for (int f = 0; f < 4; ++f) {
                int row = f * 16 + ln;   // d
                int e = row * 64 + (((g + 4 * kvh) ^ (ln & 7)) * 8);
                short8 bh = *(const short8*)&Vh[e];
                short8 bl = *(const short8*)&Vl[e];
                oacc[f] = MFMA(ph, bh, oacc[f]);
                oacc[f] = MFMA(ph, bl, oacc[f]);
                oacc[f] = MFMA(pl, bh, oacc[f]);
            }
        }
        __syncthreads();   // V/P reads done before next staging
    }

    // epilogue: normalize, store bf16 hi/lo at [b][q][c]
    float inv[4];
    #pragma unroll
    for (int r = 0; r < 4; ++r) inv[r] = 1.f / l_run[r];
    #pragma unroll
    for (int f = 0; f < 4; ++f) {
        #pragma unroll
        for (int r = 0; r < 4; ++r) {
            float v = oacc[f][r] * inv[r];
            size_t ge = ((size_t)b * TQ_ + qbase + 16 * w + 4 * g + r) * C_ + h * DH_ + f * 16 + ln;
            unsigned short hh = f2bf(v);
            ohi[ge] = hh; olo[ge] = f2bf(v - bf2f(hh));
        }
    }
}

// ---------------------------------------------------------------------------
// ws carve (bytes), ~102 MB total:
//   region0: yq fp32 (33.55MB)  -- reused as o_hi|o_lo (attn out; yq dead by then)
//   yk, yv fp32 (8.39MB ea) | q_hi,q_lo (16.78MB ea) | k/v planes (4.19MB ea)
//   8 weight planes (128KB ea)
// ---------------------------------------------------------------------------
extern "C" void kernel_launch(void* const* d_in, const int* in_sizes, int n_in,
                              void* d_out, int out_size, void* d_ws, size_t ws_size,
                              hipStream_t stream) {
    const float* x     = (const float*)d_in[0];
    const float* dw_q  = (const float*)d_in[1];
    const float* g_q   = (const float*)d_in[2];
    const float* b_q   = (const float*)d_in[3];
    const float* m_q   = (const float*)d_in[4];
    const float* v_q   = (const float*)d_in[5];
    const float* pw_q  = (const float*)d_in[6];
    const float* dw_k  = (const float*)d_in[7];
    const float* g_k   = (const float*)d_in[8];
    const float* b_k   = (const float*)d_in[9];
    const float* m_k   = (const float*)d_in[10];
    const float* v_k   = (const float*)d_in[11];
    const float* pw_k  = (const float*)d_in[12];
    const float* dw_v  = (const float*)d_in[13];
    const float* g_v   = (const float*)d_in[14];
    const float* b_v   = (const float*)d_in[15];
    const float* m_v   = (const float*)d_in[16];
    const float* v_v   = (const float*)d_in[17];
    const float* pw_v  = (const float*)d_in[18];
    const float* projw = (const float*)d_in[19];
    const float* projb = (const float*)d_in[20];
    float* out = (float*)d_out;

    const size_t NQ = (size_t)B_ * TQ_ * C_;    // 8388608
    const size_t NK = (size_t)B_ * TKV_ * C_;   // 2097152
    const size_t NW = (size_t)C_ * C_;          // 65536
    char* wsb = (char*)d_ws;
    float* yq = (float*)wsb;                        // NQ floats
    unsigned short* o_hi = (unsigned short*)wsb;    // overlaps yq (dead by attn)
    unsigned short* o_lo = o_hi + NQ;
    size_t off = NQ * 4;
    float* yk = (float*)(wsb + off); off += NK * 4;
    float* yv = (float*)(wsb + off); off += NK * 4;
    unsigned short* q_hi = (unsigned short*)(wsb + off); off += NQ * 2;
    unsigned short* q_lo = (unsigned short*)(wsb + off); off += NQ * 2;
    unsigned short* k_hi = (unsigned short*)(wsb + off); off += NK * 2;
    unsigned short* k_lo = (unsigned short*)(wsb + off); off += NK * 2;
    unsigned short* v_hi = (unsigned short*)(wsb + off); off += NK * 2;
    unsigned short* v_lo = (unsigned short*)(wsb + off); off += NK * 2;
    unsigned short* wq_hi = (unsigned short*)(wsb + off); off += NW * 2;
    unsigned short* wq_lo = (unsigned short*)(wsb + off); off += NW * 2;
    unsigned short* wk_hi = (unsigned short*)(wsb + off); off += NW * 2;
    unsigned short* wk_lo = (unsigned short*)(wsb + off); off += NW * 2;
    unsigned short* wv_hi = (unsigned short*)(wsb + off); off += NW * 2;
    unsigned short* wv_lo = (unsigned short*)(wsb + off); off += NW * 2;
    unsigned short* wp_hi = (unsigned short*)(wsb + off); off += NW * 2;
    unsigned short* wp_lo = (unsigned short*)(wsb + off); off += NW * 2;

    // weight pre-split: all 4 matrices, one launch
    w2bf4_kernel<<<dim3(64, 4), 256, 0, stream>>>(
        pw_q, pw_k, pw_v, projw,
        wq_hi, wq_lo, wk_hi, wk_lo, wv_hi, wv_lo, wp_hi, wp_lo);
    // all three dw+BN paths, one launch (x fetched once, shared via L2/L3)
    dwbn3_kernel<<<49152, 256, 0, stream>>>(
        x,
        dw_q, g_q, b_q, m_q, v_q, yq,
        dw_k, g_k, b_k, m_k, v_k, yk,
        dw_v, g_v, b_v, m_v, v_v, yv);
    // pointwise projections
    pw_mfma<0, 0><<<dim3(TQ_ / 64, 4, B_), 256, 0, stream>>>(
        wq_hi, wq_lo, yq, nullptr, nullptr, q_hi, q_lo, nullptr, nullptr, TQ_);
    pw_mfma<0, 0><<<dim3(TKV_ / 64, 4, B_), 256, 0, stream>>>(
        wk_hi, wk_lo, yk, nullptr, nullptr, k_hi, k_lo, nullptr, nullptr, TKV_);
    pw_mfma<0, 1><<<dim3(TKV_ / 64, 4, B_), 256, 0, stream>>>(
        wv_hi, wv_lo, yv, nullptr, nullptr, v_hi, v_lo, nullptr, nullptr, TKV_);
    // attention
    attn_mfma<<<dim3(TQ_ / 64, HEADS_, B_), 256, 0, stream>>>(
        q_hi, q_lo, k_hi, k_lo, v_hi, v_lo, o_hi, o_lo);
    // output projection + bias (B staged via global_load_lds from bf16 o)
    pw_mfma<1, 2><<<dim3(TQ_ / 64, 4, B_), 256, 0, stream>>>(
        wp_hi, wp_lo, nullptr, o_hi, o_lo, nullptr, nullptr, out, projb, TQ_);
}

// Round 11
// 411.709 us; speedup vs baseline: 1.0304x; 1.0304x over previous
//
#include <hip/hip_runtime.h>

#define B_     8
#define C_     256
#define H_     64
#define W_     64
#define HEADS_ 4
#define DH_    64
#define TQ_    4096   // 64*64 query pixels
#define TKV_   1024   // 32*32 kv pixels
#define EPS_   1e-5f
#define SCALE_ 0.0625f  // 256^-0.5
#define THR_   8.0f     // defer-max rescale threshold (P bounded by e^8)

typedef __attribute__((ext_vector_type(8))) short short8;
typedef __attribute__((ext_vector_type(4))) float f32x4;

#define MFMA(a, b, c) __builtin_amdgcn_mfma_f32_16x16x32_bf16((a), (b), (c), 0, 0, 0)

static __device__ __forceinline__ unsigned short f2bf(float x) {
    unsigned u = __float_as_uint(x);
    u += 0x7fff + ((u >> 16) & 1);          // round-to-nearest-even
    return (unsigned short)(u >> 16);
}
static __device__ __forceinline__ float bf2f(unsigned short h) {
    return __uint_as_float(((unsigned)h) << 16);
}
// async global->LDS, 16B per lane; LDS dest is wave-uniform base + lane*16
#define GLOAD16(gp, lp) __builtin_amdgcn_global_load_lds(                      \
    (const __attribute__((address_space(1))) void*)(gp),                       \
    (__attribute__((address_space(3))) void*)(lp), 16, 0, 0)

// ---------------------------------------------------------------------------
// one-shot fp32 -> bf16 hi/lo split of the 4 weight matrices (row-major kept)
// grid (64, 4): blockIdx.y selects the matrix
// ---------------------------------------------------------------------------
__global__ __launch_bounds__(256)
void w2bf4_kernel(const float* __restrict__ w0, const float* __restrict__ w1,
                  const float* __restrict__ w2, const float* __restrict__ w3,
                  unsigned short* __restrict__ h0, unsigned short* __restrict__ l0,
                  unsigned short* __restrict__ h1, unsigned short* __restrict__ l1,
                  unsigned short* __restrict__ h2, unsigned short* __restrict__ l2,
                  unsigned short* __restrict__ h3, unsigned short* __restrict__ l3) {
    int m = blockIdx.y;
    const float* wm = (m == 0) ? w0 : (m == 1) ? w1 : (m == 2) ? w2 : w3;
    unsigned short* whi = (m == 0) ? h0 : (m == 1) ? h1 : (m == 2) ? h2 : h3;
    unsigned short* wlo = (m == 0) ? l0 : (m == 1) ? l1 : (m == 2) ? l2 : l3;
    int idx = (blockIdx.x * 256 + threadIdx.x) * 4;
    const float4 v4 = *(const float4*)&wm[idx];
    float vv[4] = {v4.x, v4.y, v4.z, v4.w};
    unsigned short hh[4], ll[4];
    #pragma unroll
    for (int j = 0; j < 4; ++j) { hh[j] = f2bf(vv[j]); ll[j] = f2bf(vv[j] - bf2f(hh[j])); }
    *(ushort4*)&whi[idx] = make_ushort4(hh[0], hh[1], hh[2], hh[3]);
    *(ushort4*)&wlo[idx] = make_ushort4(ll[0], ll[1], ll[2], ll[3]);
}

// ---------------------------------------------------------------------------
// all three depthwise 3x3 + BN paths in ONE launch; block range selects path.
//   [0,32768)      : q path, stride 1, 64x64 -> yq
//   [32768,40960)  : k path, stride 2, 32x32 -> yk
//   [40960,49152)  : v path, stride 2, 32x32 -> yv
// out layout [b][c][p]
// ---------------------------------------------------------------------------
__global__ __launch_bounds__(256)
void dwbn3_kernel(const float* __restrict__ x,
                  const float* __restrict__ dwq, const float* __restrict__ gq,
                  const float* __restrict__ bq,  const float* __restrict__ mq,
                  const float* __restrict__ vq,  float* __restrict__ yq,
                  const float* __restrict__ dwk, const float* __restrict__ gk,
                  const float* __restrict__ bk,  const float* __restrict__ mk,
                  const float* __restrict__ vk,  float* __restrict__ yk,
                  const float* __restrict__ dwv, const float* __restrict__ gv,
                  const float* __restrict__ bv,  const float* __restrict__ mv,
                  const float* __restrict__ vv,  float* __restrict__ yv) {
    int bid = blockIdx.x;
    const float *dw, *g, *bet, *mu, *var;
    float* y;
    int stride, Ho, Wo, base;
    if (bid < 32768) {
        dw = dwq; g = gq; bet = bq; mu = mq; var = vq; y = yq;
        stride = 1; Ho = 64; Wo = 64; base = 0;
    } else if (bid < 40960) {
        dw = dwk; g = gk; bet = bk; mu = mk; var = vk; y = yk;
        stride = 2; Ho = 32; Wo = 32; base = 32768;
    } else {
        dw = dwv; g = gv; bet = bv; mu = mv; var = vv; y = yv;
        stride = 2; Ho = 32; Wo = 32; base = 40960;
    }
    int idx = (bid - base) * 256 + threadIdx.x;
    int ow = idx % Wo;
    int t  = idx / Wo;
    int oh = t % Ho; t /= Ho;
    int c  = t % C_;
    int b  = t / C_;
    const float* xp = x + ((size_t)(b * C_ + c)) * H_ * W_;
    const float* wp = dw + c * 9;
    int ih0 = oh * stride - 1, iw0 = ow * stride - 1;
    float acc = 0.f;
    #pragma unroll
    for (int kh = 0; kh < 3; ++kh) {
        int ih = ih0 + kh;
        if (ih < 0 || ih >= H_) continue;
        #pragma unroll
        for (int kw = 0; kw < 3; ++kw) {
            int iw = iw0 + kw;
            if (iw < 0 || iw >= W_) continue;
            acc = fmaf(xp[ih * W_ + iw], wp[kh * 3 + kw], acc);
        }
    }
    float inv = g[c] * __frsqrt_rn(var[c] + EPS_);
    y[idx] = (acc - mu[c]) * inv + bet[c];
}

// ---------------------------------------------------------------------------
// pointwise GEMM on MFMA, split-bf16 (hi/lo, 3 products), per batch:
//   D[o][p] = sum_c W[o][c] * Y[c][p]
// (unchanged this round — frozen so per-dispatch timings attribute cleanly)
// ---------------------------------------------------------------------------
template<int IN_BF16, int OUT_MODE>
__global__ __launch_bounds__(256, 2)
void pw_mfma(const unsigned short* __restrict__ whi, const unsigned short* __restrict__ wlo,
             const float* __restrict__ yf32,
             const unsigned short* __restrict__ yhi, const unsigned short* __restrict__ ylo,
             unsigned short* __restrict__ ohi, unsigned short* __restrict__ olo,
             float* __restrict__ of32, const float* __restrict__ bias, int Np) {
    __shared__ unsigned short Ah[64 * 64], Al[64 * 64];
    __shared__ unsigned short Bh[64 * 64], Bl[64 * 64];
    __shared__ float scr[64 * 64];   // fp32 staging / epilogue transpose (swizzled)

    const int tid = threadIdx.x;
    const int l = tid & 63, w = tid >> 6;
    const int g = l >> 4, ln = l & 15;
    const int pbase = blockIdx.x * 64;
    const int obase = blockIdx.y * 64;
    const int b = blockIdx.z;

    f32x4 acc[4];
    #pragma unroll
    for (int f = 0; f < 4; ++f) acc[f] = (f32x4){0.f, 0.f, 0.f, 0.f};

    for (int c0 = 0; c0 < C_; c0 += 64) {
        // ---- stage A: pre-split W bf16 [o][c] via global_load_lds ----
        #pragma unroll
        for (int ii = 0; ii < 4; ++ii) {
            int ch = w * 4 + ii;  // 0..15: 0-7 hi, 8-15 lo
            const unsigned short* src = (ch < 8) ? whi : wlo;
            unsigned short* dst = (ch < 8) ? Ah : Al;
            int i = ch & 7;
            size_t ge = (size_t)(obase + i * 8 + (l >> 3)) * C_ + c0 +
                        (((l & 7) ^ ((l >> 3) & 7)) * 8);
            GLOAD16(src + ge, dst + i * 512);
        }
        if constexpr (IN_BF16) {
            // ---- stage B: bf16 [p][c] via global_load_lds, source-chunk XOR ----
            #pragma unroll
            for (int ii = 0; ii < 4; ++ii) {
                int ch = w * 4 + ii;
                const unsigned short* src = (ch < 8) ? yhi : ylo;
                unsigned short* dst = (ch < 8) ? Bh : Bl;
                int i = ch & 7;
                size_t ge = ((size_t)b * Np + pbase + i * 8 + (l >> 3)) * C_ + c0 +
                            (((l & 7) ^ ((l >> 3) & 7)) * 8);
                GLOAD16(src + ge, dst + i * 512);
            }
        } else {
            // ---- stage scratch: Y fp32 [c][p] tile, coalesced ----
            #pragma unroll
            for (int pass = 0; pass < 4; ++pass) {
                int idx = tid + pass * 256;
                int cr = idx >> 4, p4 = (idx & 15) * 4;
                *(float4*)&scr[cr * 64 + p4] =
                    *(const float4*)&yf32[(size_t)b * C_ * Np + (size_t)(c0 + cr) * Np + pbase + p4];
            }
        }
        __syncthreads();
        if constexpr (!IN_BF16) {
            // ---- transpose + convert: scratch [c][p] -> B hi/lo [p][c] swizzled ----
            int p = tid & 63, cq = tid >> 6;
            #pragma unroll
            for (int jj = 0; jj < 4; ++jj) {
                unsigned short hh[4], ll[4];
                #pragma unroll
                for (int j = 0; j < 4; ++j) {
                    float v = scr[(cq * 16 + jj * 4 + j) * 64 + p];
                    hh[j] = f2bf(v); ll[j] = f2bf(v - bf2f(hh[j]));
                }
                int cl = cq * 16 + jj * 4;
                int e = p * 64 + (((cl >> 3) ^ (p & 7)) * 8) + (cl & 7);
                *(ushort4*)&Bh[e] = make_ushort4(hh[0], hh[1], hh[2], hh[3]);
                *(ushort4*)&Bl[e] = make_ushort4(ll[0], ll[1], ll[2], ll[3]);
            }
            __syncthreads();
        }
        // ---- compute: 24 MFMA per K-chunk per wave ----
        #pragma unroll
        for (int kh = 0; kh < 2; ++kh) {
            int gc = kh * 4 + g;
            int ea = (16 * w + ln) * 64 + ((gc ^ (ln & 7)) * 8);
            short8 ah = *(const short8*)&Ah[ea];
            short8 al = *(const short8*)&Al[ea];
            #pragma unroll
            for (int f = 0; f < 4; ++f) {
                int p = f * 16 + ln;
                int eb = p * 64 + ((gc ^ (p & 7)) * 8);
                short8 bh = *(const short8*)&Bh[eb];
                short8 bl = *(const short8*)&Bl[eb];
                acc[f] = MFMA(ah, bh, acc[f]);
                acc[f] = MFMA(ah, bl, acc[f]);
                acc[f] = MFMA(al, bh, acc[f]);
            }
        }
        __syncthreads();
    }

    // ---- epilogues ----
    if constexpr (OUT_MODE == 0) {
        // transpose D [o][p] -> [p][o] via swizzled LDS, store bf16 hi/lo [b][p][o]
        #pragma unroll
        for (int f = 0; f < 4; ++f) {
            int p = f * 16 + ln;
            #pragma unroll
            for (int r = 0; r < 4; ++r) {
                int o = 16 * w + 4 * g + r;
                scr[p * 64 + (o ^ (4 * (p & 7)))] = acc[f][r];
            }
        }
        __syncthreads();
        int p = tid & 63, oq = tid >> 6;
        #pragma unroll
        for (int jj = 0; jj < 4; ++jj) {
            unsigned short hh[4], ll[4];
            #pragma unroll
            for (int j = 0; j < 4; ++j) {
                float v = scr[p * 64 + ((oq * 16 + jj * 4 + j) ^ (4 * (p & 7)))];
                hh[j] = f2bf(v); ll[j] = f2bf(v - bf2f(hh[j]));
            }
            size_t ge = ((size_t)b * Np + pbase + p) * C_ + obase + oq * 16 + jj * 4;
            *(ushort4*)&ohi[ge] = make_ushort4(hh[0], hh[1], hh[2], hh[3]);
            *(ushort4*)&olo[ge] = make_ushort4(ll[0], ll[1], ll[2], ll[3]);
        }
    } else if constexpr (OUT_MODE == 1) {
        #pragma unroll
        for (int f = 0; f < 4; ++f) {
            int p = pbase + f * 16 + ln;
            #pragma unroll
            for (int r = 0; r < 4; ++r) {
                int o = obase + 16 * w + 4 * g + r;
                size_t ge = ((size_t)b * C_ + o) * Np + p;
                float v = acc[f][r];
                unsigned short hh = f2bf(v);
                ohi[ge] = hh; olo[ge] = f2bf(v - bf2f(hh));
            }
        }
    } else {
        float bv[4];
        #pragma unroll
        for (int r = 0; r < 4; ++r) bv[r] = bias[obase + 16 * w + 4 * g + r];
        #pragma unroll
        for (int f = 0; f < 4; ++f) {
            int p = pbase + f * 16 + ln;
            #pragma unroll
            for (int r = 0; r < 4; ++r) {
                int o = obase + 16 * w + 4 * g + r;
                of32[((size_t)b * C_ + o) * Np + p] = acc[f][r] + bv[r];
            }
        }
    }
}

// ---------------------------------------------------------------------------
// flash attention on MFMA, split-bf16 — round-11 rework:
//  * K/V double-buffered; next tile's global_load_lds issued right after the
//    top barrier (overlaps QK^T+softmax). Barriers 3 -> 2 per iter.
//  * deferred-sum softmax: per-lane partial l (corr is group-uniform), one
//    16-lane reduce in epilogue (was 4 shfl per row per iter).
//  * group defer-max (THR=8): ballot over the 16-lane row-group; fast path
//    skips max-reduce + rescale entirely. First iter always slow (m=-1e30).
// LDS: K/V hi/lo x2 bufs = 64KB + P 16KB = 80KB -> 2 blocks/CU.
// ---------------------------------------------------------------------------
__global__ __launch_bounds__(256, 2)
void attn_mfma(const unsigned short* __restrict__ qhi, const unsigned short* __restrict__ qlo,
               const unsigned short* __restrict__ khi, const unsigned short* __restrict__ klo,
               const unsigned short* __restrict__ vhi, const unsigned short* __restrict__ vlo,
               unsigned short* __restrict__ ohi, unsigned short* __restrict__ olo) {
    __shared__ unsigned short Kh[2 * 64 * 64], Kl[2 * 64 * 64];
    __shared__ unsigned short Vh[2 * 64 * 64], Vl[2 * 64 * 64];
    __shared__ unsigned short Ph[64 * 64], Pl[64 * 64];

    const int tid = threadIdx.x, l = tid & 63, w = tid >> 6;
    const int g = l >> 4, ln = l & 15;
    const int qbase = blockIdx.x * 64;
    const int h = blockIdx.y, b = blockIdx.z;

    // Q fragments in regs: [16q x 64d] per wave, hi/lo x 2 k-halves
    short8 qh[2], ql[2];
    {
        size_t base = ((size_t)b * TQ_ + qbase + 16 * w + ln) * C_ + h * DH_ + g * 8;
        qh[0] = *(const short8*)&qhi[base];
        qh[1] = *(const short8*)&qhi[base + 32];
        ql[0] = *(const short8*)&qlo[base];
        ql[1] = *(const short8*)&qlo[base + 32];
    }
    f32x4 oacc[4];
    float m_run[4], lpart[4];
    #pragma unroll
    for (int f = 0; f < 4; ++f) oacc[f] = (f32x4){0.f, 0.f, 0.f, 0.f};
    #pragma unroll
    for (int r = 0; r < 4; ++r) { m_run[r] = -1e30f; lpart[r] = 0.f; }

    // staging setup: wave w owns one plane; per-iter 8 chunks of 1KB
    const int swz = ((l & 7) ^ ((l >> 3) & 7)) * 8;
    const unsigned short* ssrc = (w == 0) ? khi : (w == 1) ? klo : (w == 2) ? vhi : vlo;
    unsigned short* sdst0 = (w == 0) ? Kh : (w == 1) ? Kl : (w == 2) ? Vh : Vl;
    const size_t sstride = (w < 2) ? (size_t)C_ : (size_t)TKV_;
    const size_t sgbase  = (w < 2) ? ((size_t)b * TKV_) * C_ + h * DH_
                                   : ((size_t)b * C_ + h * DH_) * TKV_;
    auto STAGE = [&](int sel, int kt) {
        size_t ko = (w < 2) ? (size_t)kt * C_ : (size_t)kt;
        unsigned short* dst = sdst0 + sel * 4096;
        #pragma unroll
        for (int i = 0; i < 8; ++i)
            GLOAD16(ssrc + sgbase + ko + (size_t)(i * 8 + (l >> 3)) * sstride + swz,
                    dst + i * 512);
    };

    STAGE(0, 0);
    for (int it = 0; it < TKV_ / 64; ++it) {
        const int cur = it & 1, so = cur * 4096;
        __syncthreads();                       // staged tile ready (vmcnt drained)
        if (it + 1 < TKV_ / 64) STAGE(cur ^ 1, (it + 1) * 64);   // prefetch overlap

        // S = Q K^T: per wave 16q x 64kv
        f32x4 sacc[4];
        #pragma unroll
        for (int f = 0; f < 4; ++f) sacc[f] = (f32x4){0.f, 0.f, 0.f, 0.f};
        #pragma unroll
        for (int kh = 0; kh < 2; ++kh) {
            #pragma unroll
            for (int f = 0; f < 4; ++f) {
                int row = f * 16 + ln;   // kv
                int e = so + row * 64 + (((g + 4 * kh) ^ (ln & 7)) * 8);
                short8 bh = *(const short8*)&Kh[e];
                short8 bl = *(const short8*)&Kl[e];
                sacc[f] = MFMA(qh[kh], bh, sacc[f]);
                sacc[f] = MFMA(qh[kh], bl, sacc[f]);
                sacc[f] = MFMA(ql[kh], bh, sacc[f]);
            }
        }

        // ---- softmax: deferred-sum + group defer-max ----
        float pmax[4];
        bool allc = true;
        #pragma unroll
        for (int r = 0; r < 4; ++r) {
            float mm = fmaxf(fmaxf(sacc[0][r], sacc[1][r]), fmaxf(sacc[2][r], sacc[3][r]));
            pmax[r] = mm * SCALE_;
            allc = allc && (pmax[r] <= m_run[r] + THR_);
        }
        unsigned long long bb = __ballot(allc);
        bool fast = (((bb >> (g * 16)) & 0xFFFFull) == 0xFFFFull);
        if (!fast) {
            #pragma unroll
            for (int r = 0; r < 4; ++r) {
                float mm = pmax[r];
                #pragma unroll
                for (int off = 1; off < 16; off <<= 1) mm = fmaxf(mm, __shfl_xor(mm, off, 16));
                float mnew = fmaxf(m_run[r], mm);
                float corr = __expf(m_run[r] - mnew);
                m_run[r] = mnew;
                lpart[r] *= corr;
                #pragma unroll
                for (int f = 0; f < 4; ++f) oacc[f][r] *= corr;
            }
        }
        #pragma unroll
        for (int r = 0; r < 4; ++r) {
            int q = 16 * w + 4 * g + r;
            #pragma unroll
            for (int f = 0; f < 4; ++f) {
                float pv = __expf(fmaf(sacc[f][r], SCALE_, -m_run[r]));
                lpart[r] += pv;
                unsigned short hh = f2bf(pv);
                int e = q * 64 + (((f * 2 + (ln >> 3)) ^ (q & 7)) * 8) + (ln & 7);
                Ph[e] = hh;
                Pl[e] = f2bf(pv - bf2f(hh));
            }
        }
        __syncthreads();   // P visible (wave-private but keep cross-wave alignment safety)

        // O += P V: per wave 16q x 64d
        #pragma unroll
        for (int kvh = 0; kvh < 2; ++kvh) {
            int qr = 16 * w + ln;
            int pe = qr * 64 + (((kvh * 4 + g) ^ (qr & 7)) * 8);
            short8 ph = *(const short8*)&Ph[pe];
            short8 pl = *(const short8*)&Pl[pe];
            #pragma unroll
            for (int f = 0; f < 4; ++f) {
                int row = f * 16 + ln;   // d
                int e = so + row * 64 + (((g + 4 * kvh) ^ (ln & 7)) * 8);
                short8 bh = *(const short8*)&Vh[e];
                short8 bl = *(const short8*)&Vl[e];
                oacc[f] = MFMA(ph, bh, oacc[f]);
                oacc[f] = MFMA(ph, bl, oacc[f]);
                oacc[f] = MFMA(pl, bh, oacc[f]);
            }
        }
        // no trailing barrier: next staging targets the other buffer; the top
        // barrier of iter it+1 orders V[cur] reads vs staging into cur at it+2
    }

    // epilogue: reduce per-lane partial sums once, normalize, store bf16 hi/lo
    float inv[4];
    #pragma unroll
    for (int r = 0; r < 4; ++r) {
        float s = lpart[r];
        #pragma unroll
        for (int off = 1; off < 16; off <<= 1) s += __shfl_xor(s, off, 16);
        inv[r] = 1.f / s;
    }
    #pragma unroll
    for (int f = 0; f < 4; ++f) {
        #pragma unroll
        for (int r = 0; r < 4; ++r) {
            float v = oacc[f][r] * inv[r];
            size_t ge = ((size_t)b * TQ_ + qbase + 16 * w + 4 * g + r) * C_ + h * DH_ + f * 16 + ln;
            unsigned short hh = f2bf(v);
            ohi[ge] = hh; olo[ge] = f2bf(v - bf2f(hh));
        }
    }
}

// ---------------------------------------------------------------------------
// ws carve (bytes), ~102 MB total:
//   region0: yq fp32 (33.55MB)  -- reused as o_hi|o_lo (attn out; yq dead by then)
//   yk, yv fp32 (8.39MB ea) | q_hi,q_lo (16.78MB ea) | k/v planes (4.19MB ea)
//   8 weight planes (128KB ea)
// ---------------------------------------------------------------------------
extern "C" void kernel_launch(void* const* d_in, const int* in_sizes, int n_in,
                              void* d_out, int out_size, void* d_ws, size_t ws_size,
                              hipStream_t stream) {
    const float* x     = (const float*)d_in[0];
    const float* dw_q  = (const float*)d_in[1];
    const float* g_q   = (const float*)d_in[2];
    const float* b_q   = (const float*)d_in[3];
    const float* m_q   = (const float*)d_in[4];
    const float* v_q   = (const float*)d_in[5];
    const float* pw_q  = (const float*)d_in[6];
    const float* dw_k  = (const float*)d_in[7];
    const float* g_k   = (const float*)d_in[8];
    const float* b_k   = (const float*)d_in[9];
    const float* m_k   = (const float*)d_in[10];
    const float* v_k   = (const float*)d_in[11];
    const float* pw_k  = (const float*)d_in[12];
    const float* dw_v  = (const float*)d_in[13];
    const float* g_v   = (const float*)d_in[14];
    const float* b_v   = (const float*)d_in[15];
    const float* m_v   = (const float*)d_in[16];
    const float* v_v   = (const float*)d_in[17];
    const float* pw_v  = (const float*)d_in[18];
    const float* projw = (const float*)d_in[19];
    const float* projb = (const float*)d_in[20];
    float* out = (float*)d_out;

    const size_t NQ = (size_t)B_ * TQ_ * C_;    // 8388608
    const size_t NK = (size_t)B_ * TKV_ * C_;   // 2097152
    const size_t NW = (size_t)C_ * C_;          // 65536
    char* wsb = (char*)d_ws;
    float* yq = (float*)wsb;                        // NQ floats
    unsigned short* o_hi = (unsigned short*)wsb;    // overlaps yq (dead by attn)
    unsigned short* o_lo = o_hi + NQ;
    size_t off = NQ * 4;
    float* yk = (float*)(wsb + off); off += NK * 4;
    float* yv = (float*)(wsb + off); off += NK * 4;
    unsigned short* q_hi = (unsigned short*)(wsb + off); off += NQ * 2;
    unsigned short* q_lo = (unsigned short*)(wsb + off); off += NQ * 2;
    unsigned short* k_hi = (unsigned short*)(wsb + off); off += NK * 2;
    unsigned short* k_lo = (unsigned short*)(wsb + off); off += NK * 2;
    unsigned short* v_hi = (unsigned short*)(wsb + off); off += NK * 2;
    unsigned short* v_lo = (unsigned short*)(wsb + off); off += NK * 2;
    unsigned short* wq_hi = (unsigned short*)(wsb + off); off += NW * 2;
    unsigned short* wq_lo = (unsigned short*)(wsb + off); off += NW * 2;
    unsigned short* wk_hi = (unsigned short*)(wsb + off); off += NW * 2;
    unsigned short* wk_lo = (unsigned short*)(wsb + off); off += NW * 2;
    unsigned short* wv_hi = (unsigned short*)(wsb + off); off += NW * 2;
    unsigned short* wv_lo = (unsigned short*)(wsb + off); off += NW * 2;
    unsigned short* wp_hi = (unsigned short*)(wsb + off); off += NW * 2;
    unsigned short* wp_lo = (unsigned short*)(wsb + off); off += NW * 2;

    // weight pre-split: all 4 matrices, one launch
    w2bf4_kernel<<<dim3(64, 4), 256, 0, stream>>>(
        pw_q, pw_k, pw_v, projw,
        wq_hi, wq_lo, wk_hi, wk_lo, wv_hi, wv_lo, wp_hi, wp_lo);
    // all three dw+BN paths, one launch (x fetched once, shared via L2/L3)
    dwbn3_kernel<<<49152, 256, 0, stream>>>(
        x,
        dw_q, g_q, b_q, m_q, v_q, yq,
        dw_k, g_k, b_k, m_k, v_k, yk,
        dw_v, g_v, b_v, m_v, v_v, yv);
    // pointwise projections
    pw_mfma<0, 0><<<dim3(TQ_ / 64, 4, B_), 256, 0, stream>>>(
        wq_hi, wq_lo, yq, nullptr, nullptr, q_hi, q_lo, nullptr, nullptr, TQ_);
    pw_mfma<0, 0><<<dim3(TKV_ / 64, 4, B_), 256, 0, stream>>>(
        wk_hi, wk_lo, yk, nullptr, nullptr, k_hi, k_lo, nullptr, nullptr, TKV_);
    pw_mfma<0, 1><<<dim3(TKV_ / 64, 4, B_), 256, 0, stream>>>(
        wv_hi, wv_lo, yv, nullptr, nullptr, v_hi, v_lo, nullptr, nullptr, TKV_);
    // attention
    attn_mfma<<<dim3(TQ_ / 64, HEADS_, B_), 256, 0, stream>>>(
        q_hi, q_lo, k_hi, k_lo, v_hi, v_lo, o_hi, o_lo);
    // output projection + bias (B staged via global_load_lds from bf16 o)
    pw_mfma<1, 2><<<dim3(TQ_ / 64, 4, B_), 256, 0, stream>>>(
        wp_hi, wp_lo, nullptr, o_hi, o_lo, nullptr, nullptr, out, projb, TQ_);
}